// Round 7
// baseline (3773.905 us; speedup 1.0000x reference)
//
#include <hip/hip_runtime.h>

#define H    64
#define TT   1024
#define GSP  584    // gate buffer row stride (floats); 584 % 32 == 8; 16B-aligned rows
#define HRUS 144    // h array row stride in ushorts (288 B = 72 dwords; 72 % 32 == 8)

typedef float  f32x4  __attribute__((ext_vector_type(4)));
typedef __bf16 bf16x8 __attribute__((ext_vector_type(8)));

__device__ __forceinline__ unsigned short bf16_rne(float f) {
    unsigned u = __float_as_uint(f);
    u += 0x7FFFu + ((u >> 16) & 1u);
    return (unsigned short)(u >> 16);
}
__device__ __forceinline__ float fast_sigmoid(float x) {
    return __builtin_amdgcn_rcpf(1.0f + __expf(-x));
}
__device__ __forceinline__ float fast_tanh(float x) {
    float xx = fminf(fmaxf(x, -15.0f), 15.0f);
    float e  = __expf(2.0f * xx);
    return (e - 1.0f) * __builtin_amdgcn_rcpf(e + 1.0f);
}

#define ARGS const float* __restrict__ x, \
    const float* __restrict__ w_ih0, const float* __restrict__ w_hh0, \
    const float* __restrict__ b_ih0, const float* __restrict__ b_hh0, \
    const float* __restrict__ w_ih1, const float* __restrict__ w_hh1, \
    const float* __restrict__ b_ih1, const float* __restrict__ b_hh1, \
    const float* __restrict__ w_fc,  const float* __restrict__ b_fc,  \
    float* __restrict__ outp

// ============ ablation kernel: R4 structure (MB=8, grid 256), builtin MFMA =========
// V: 0=FULL  1=NO_MFMA (G chain + barriers + b128 reads)  2=NO_GATES (M + barriers)
//    4=SKELETON (barriers + LDS reads/writes only)
template<int V>
__global__ __launch_bounds__(512, 2) void gru_abl(ARGS)
{
    __shared__ __align__(16) float          xs[8 * TT];
    __shared__ __align__(16) float          gA[8 * GSP];
    __shared__ __align__(16) unsigned short hA[16 * HRUS];

    const int tid  = threadIdx.x;
    const int wave = tid >> 6;
    const int lane = tid & 63;
    const int r    = lane & 15;
    const int q    = lane >> 4;
    const int b0g  = blockIdx.x * 8;

    for (int i = tid; i < 16*HRUS; i += 512) hA[i] = 0;
    for (int i = tid; i < 8*GSP;  i += 512) gA[i] = 0.0f;

    {
        const float* xrow = x + (size_t)(b0g + wave) * TT;
        float* xd = xs + wave * TT;
        #pragma unroll
        for (int u = 0; u < 4; ++u) {
            int idx = (u * 64 + lane) * 4;
            *(float4*)(xd + idx) = *(const float4*)(xrow + idx);
        }
    }

    bf16x8 whi[5][2], wlo[5][2];
    int doff[5]; bool wr_ok[5];
    #pragma unroll
    for (int i = 0; i < 5; ++i) {
        const int n = 5 * wave + i;
        const float* W; int gr;
        if      (n < 12) { W = w_hh0; gr = 16 * n; }
        else if (n < 24) { W = w_ih1; gr = 16 * (n - 12); }
        else if (n < 36) { W = w_hh1; gr = 16 * (n - 24); }
        else             { W = w_hh0; gr = 0; }
        #pragma unroll
        for (int c = 0; c < 2; ++c) {
            const float* wp = W + (gr + r) * H + 32 * c + 8 * q;
            float4 p0 = *(const float4*)wp;
            float4 p1 = *(const float4*)(wp + 4);
            float f[8] = {p0.x,p0.y,p0.z,p0.w,p1.x,p1.y,p1.z,p1.w};
            unsigned short uh[8], ul[8];
            #pragma unroll
            for (int j = 0; j < 8; ++j) {
                unsigned short h16 = bf16_rne(f[j]);
                uh[j] = h16;
                ul[j] = bf16_rne(f[j] - __uint_as_float((unsigned)h16 << 16));
            }
            whi[i][c] = *(const bf16x8*)uh;
            wlo[i][c] = *(const bf16x8*)ul;
        }
        doff [i] = (r & 7) * GSP + 16 * n + 4 * q;
        wr_ok[i] = (n < 36) && ((n < 24) == (r < 8));
    }

    const unsigned short* hp0 = hA + r * HRUS + 8 * q;
    const unsigned short* hp1 = hA + r * HRUS + 8 * (4 + q);
    const unsigned short* hp2 = hp0 + 64;
    const unsigned short* hp3 = hp1 + 64;

    unsigned short* p0h = hA + wave * HRUS + lane;
    unsigned short* p0l = p0h + 64;
    unsigned short* p1h = hA + (wave + 8) * HRUS + lane;
    unsigned short* p1l = p1h + 64;

    const float* gp  = gA + wave * GSP;
    const float* xmy = xs + wave * TT;

    const float wi0r = w_ih0[lane], wi0z = w_ih0[64+lane], wi0n = w_ih0[128+lane];
    const float c0r  = b_ih0[lane]     + b_hh0[lane];
    const float c0z  = b_ih0[64+lane]  + b_hh0[64+lane];
    const float bi0n = b_ih0[128+lane], bh0n = b_hh0[128+lane];
    const float c1r  = b_ih1[lane]     + b_hh1[lane];
    const float c1z  = b_ih1[64+lane]  + b_hh1[64+lane];
    const float bi1n = b_ih1[128+lane], bh1n = b_hh1[128+lane];
    const float wfc  = w_fc[lane];

    float h0reg = 0.0f, h1reg = 0.0f;
    __syncthreads();

    #pragma unroll 1
    for (int t = 0; t < TT; ++t) {
        // ---------------- G phase ----------------
        if constexpr (V == 0 || V == 1) {
            if (t > 0) {
                float xr = gp[192+lane], xz = gp[256+lane], xn = gp[320+lane];
                float hr = gp[384+lane], hz = gp[448+lane], hn = gp[512+lane];
                float rr = fast_sigmoid(xr + hr + c1r);
                float zz = fast_sigmoid(xz + hz + c1z);
                float nn = fast_tanh(xn + bi1n + rr * (hn + bh1n));
                h1reg = fmaf(zz, h1reg - nn, nn);
                unsigned short hh = bf16_rne(h1reg);
                *p1h = hh;
                *p1l = bf16_rne(h1reg - __uint_as_float((unsigned)hh << 16));
            }
            {
                float xv  = xmy[t];
                float g0r = gp[lane], g0z = gp[64+lane], g0n = gp[128+lane];
                float rr = fast_sigmoid(fmaf(xv, wi0r, c0r) + g0r);
                float zz = fast_sigmoid(fmaf(xv, wi0z, c0z) + g0z);
                float nn = fast_tanh(fmaf(xv, wi0n, bi0n) + rr * (g0n + bh0n));
                h0reg = fmaf(zz, h0reg - nn, nn);
                unsigned short hh = bf16_rne(h0reg);
                *p0h = hh;
                *p0l = bf16_rne(h0reg - __uint_as_float((unsigned)hh << 16));
            }
        } else {   // NO_GATES / SKELETON: 2-op updates, same LDS writes
            float xv = xmy[t];
            h1reg = fmaf(h1reg, 0.9f, 0.0625f);
            unsigned short hh1_ = bf16_rne(h1reg);
            *p1h = hh1_;
            *p1l = bf16_rne(h1reg - __uint_as_float((unsigned)hh1_ << 16));
            h0reg = fmaf(h0reg, 0.9f, xv);
            unsigned short hh0_ = bf16_rne(h0reg);
            *p0h = hh0_;
            *p0l = bf16_rne(h0reg - __uint_as_float((unsigned)hh0_ << 16));
        }
        __syncthreads();

        // ---------------- M phase ----------------
        {
            const bf16x8 hhi0 = *(const bf16x8*)hp0;
            const bf16x8 hhi1 = *(const bf16x8*)hp1;
            const bf16x8 hlo0 = *(const bf16x8*)hp2;
            const bf16x8 hlo1 = *(const bf16x8*)hp3;
            if constexpr (V == 0 || V == 2) {
                #pragma unroll
                for (int i = 0; i < 5; ++i) {
                    f32x4 d = {0.0f, 0.0f, 0.0f, 0.0f};
                    d = __builtin_amdgcn_mfma_f32_16x16x32_bf16(whi[i][0], hhi0, d, 0,0,0);
                    d = __builtin_amdgcn_mfma_f32_16x16x32_bf16(whi[i][1], hhi1, d, 0,0,0);
                    d = __builtin_amdgcn_mfma_f32_16x16x32_bf16(whi[i][0], hlo0, d, 0,0,0);
                    d = __builtin_amdgcn_mfma_f32_16x16x32_bf16(whi[i][1], hlo1, d, 0,0,0);
                    d = __builtin_amdgcn_mfma_f32_16x16x32_bf16(wlo[i][0], hhi0, d, 0,0,0);
                    d = __builtin_amdgcn_mfma_f32_16x16x32_bf16(wlo[i][1], hhi1, d, 0,0,0);
                    if (wr_ok[i]) *(f32x4*)(gA + doff[i]) = d;
                }
            } else {   // keep reads live, no MFMA / stores
                asm volatile("" :: "v"(hhi0), "v"(hhi1), "v"(hlo0), "v"(hlo1));
            }
        }
        __syncthreads();
    }

    if constexpr (V == 0 || V == 1) {
        float xr = gp[192+lane], xz = gp[256+lane], xn = gp[320+lane];
        float hr = gp[384+lane], hz = gp[448+lane], hn = gp[512+lane];
        float rr = fast_sigmoid(xr + hr + c1r);
        float zz = fast_sigmoid(xz + hz + c1z);
        float nn = fast_tanh(xn + bi1n + rr * (hn + bh1n));
        h1reg = fmaf(zz, h1reg - nn, nn);
    }
    if (outp) {
        float v = h1reg * wfc;
        #pragma unroll
        for (int s = 32; s > 0; s >>= 1) v += __shfl_xor(v, s, 64);
        if (lane == 0) outp[b0g + wave] = v + b_fc[0];
    }
}

// ============ V5: MB=4, grid 512 (2 blocks/CU), wave-split gates ============
// waves 0-3: layer-0 gate for batch=wave; waves 4-7: layer-1 gate for batch=wave-4.
// hA rows: 0-3 = h0 batches, 8-11 = h1 batches (others stay zero; D cols masked).
__global__ __launch_bounds__(512, 4) void gru_v5(ARGS)
{
    __shared__ __align__(16) float          xs[4 * TT];      // 16 KB
    __shared__ __align__(16) float          gA[4 * GSP];     // 9.1 KB
    __shared__ __align__(16) unsigned short hA[16 * HRUS];   // 4.5 KB

    const int tid  = threadIdx.x;
    const int wave = tid >> 6;
    const int lane = tid & 63;
    const int r    = lane & 15;
    const int q    = lane >> 4;
    const int b0g  = blockIdx.x * 4;
    const bool L0  = (wave < 4);

    for (int i = tid; i < 16*HRUS; i += 512) hA[i] = 0;
    for (int i = tid; i < 4*GSP;  i += 512) gA[i] = 0.0f;

    if (L0) {
        const float* xrow = x + (size_t)(b0g + wave) * TT;
        float* xd = xs + wave * TT;
        #pragma unroll
        for (int u = 0; u < 4; ++u) {
            int idx = (u * 64 + lane) * 4;
            *(float4*)(xd + idx) = *(const float4*)(xrow + idx);
        }
    }

    bf16x8 whi[5][2], wlo[5][2];
    int doff[5]; bool wr_ok[5];
    #pragma unroll
    for (int i = 0; i < 5; ++i) {
        const int n = 5 * wave + i;
        const float* W; int gr;
        if      (n < 12) { W = w_hh0; gr = 16 * n; }
        else if (n < 24) { W = w_ih1; gr = 16 * (n - 12); }
        else if (n < 36) { W = w_hh1; gr = 16 * (n - 24); }
        else             { W = w_hh0; gr = 0; }
        #pragma unroll
        for (int c = 0; c < 2; ++c) {
            const float* wp = W + (gr + r) * H + 32 * c + 8 * q;
            float4 p0 = *(const float4*)wp;
            float4 p1 = *(const float4*)(wp + 4);
            float f[8] = {p0.x,p0.y,p0.z,p0.w,p1.x,p1.y,p1.z,p1.w};
            unsigned short uh[8], ul[8];
            #pragma unroll
            for (int j = 0; j < 8; ++j) {
                unsigned short h16 = bf16_rne(f[j]);
                uh[j] = h16;
                ul[j] = bf16_rne(f[j] - __uint_as_float((unsigned)h16 << 16));
            }
            whi[i][c] = *(const bf16x8*)uh;
            wlo[i][c] = *(const bf16x8*)ul;
        }
        doff [i] = (r & 7) * GSP + 16 * n + 4 * q;
        wr_ok[i] = (n < 36) && ((n < 24) == (r < 8)) && ((r & 7) < 4);
    }

    const unsigned short* hp0 = hA + r * HRUS + 8 * q;
    const unsigned short* hp1 = hA + r * HRUS + 8 * (4 + q);
    const unsigned short* hp2 = hp0 + 64;
    const unsigned short* hp3 = hp1 + 64;

    // layer0 wave b -> row b ; layer1 wave 4+b -> row 8+b (= wave+4)
    unsigned short* hwp = hA + (L0 ? wave : wave + 4) * HRUS + lane;

    const float* gbase = gA + (wave & 3) * GSP;
    const float* xmy   = xs + (wave & 3) * TT;

    const float* bi = L0 ? b_ih0 : b_ih1;
    const float* bh = L0 ? b_hh0 : b_hh1;
    const float cr  = bi[lane]      + bh[lane];
    const float cz  = bi[64+lane]   + bh[64+lane];
    const float bin = bi[128+lane];
    const float bhn = bh[128+lane];
    const float wir = L0 ? w_ih0[lane]      : 0.0f;
    const float wiz = L0 ? w_ih0[64+lane]   : 0.0f;
    const float win = L0 ? w_ih0[128+lane]  : 0.0f;
    const float wfc = w_fc[lane];

    float hreg = 0.0f;
    __syncthreads();

    #pragma unroll 1
    for (int t = 0; t < TT; ++t) {
        // ---------------- G phase (one gate set per wave) ----------------
        if (L0) {
            float xv  = xmy[t];
            float g0r = gbase[lane], g0z = gbase[64+lane], g0n = gbase[128+lane];
            float rr = fast_sigmoid(fmaf(xv, wir, cr) + g0r);
            float zz = fast_sigmoid(fmaf(xv, wiz, cz) + g0z);
            float nn = fast_tanh(fmaf(xv, win, bin) + rr * (g0n + bhn));
            hreg = fmaf(zz, hreg - nn, nn);
            unsigned short hh = bf16_rne(hreg);
            hwp[0]  = hh;
            hwp[64] = bf16_rne(hreg - __uint_as_float((unsigned)hh << 16));
        } else if (t > 0) {        // layer 1, step t-1
            float xr = gbase[192+lane], xz = gbase[256+lane], xn = gbase[320+lane];
            float hr = gbase[384+lane], hz = gbase[448+lane], hn = gbase[512+lane];
            float rr = fast_sigmoid(xr + hr + cr);
            float zz = fast_sigmoid(xz + hz + cz);
            float nn = fast_tanh(xn + bin + rr * (hn + bhn));
            hreg = fmaf(zz, hreg - nn, nn);
            unsigned short hh = bf16_rne(hreg);
            hwp[0]  = hh;
            hwp[64] = bf16_rne(hreg - __uint_as_float((unsigned)hh << 16));
        }
        __syncthreads();

        // ---------------- M phase ----------------
        {
            const bf16x8 hhi0 = *(const bf16x8*)hp0;
            const bf16x8 hhi1 = *(const bf16x8*)hp1;
            const bf16x8 hlo0 = *(const bf16x8*)hp2;
            const bf16x8 hlo1 = *(const bf16x8*)hp3;
            #pragma unroll
            for (int i = 0; i < 5; ++i) {
                f32x4 d = {0.0f, 0.0f, 0.0f, 0.0f};
                d = __builtin_amdgcn_mfma_f32_16x16x32_bf16(whi[i][0], hhi0, d, 0,0,0);
                d = __builtin_amdgcn_mfma_f32_16x16x32_bf16(whi[i][1], hhi1, d, 0,0,0);
                d = __builtin_amdgcn_mfma_f32_16x16x32_bf16(whi[i][0], hlo0, d, 0,0,0);
                d = __builtin_amdgcn_mfma_f32_16x16x32_bf16(whi[i][1], hlo1, d, 0,0,0);
                d = __builtin_amdgcn_mfma_f32_16x16x32_bf16(wlo[i][0], hhi0, d, 0,0,0);
                d = __builtin_amdgcn_mfma_f32_16x16x32_bf16(wlo[i][1], hhi1, d, 0,0,0);
                if (wr_ok[i]) *(f32x4*)(gA + doff[i]) = d;
            }
        }
        __syncthreads();
    }

    if (!L0) {   // final layer-1 gate (step TT-1) + FC
        float xr = gbase[192+lane], xz = gbase[256+lane], xn = gbase[320+lane];
        float hr = gbase[384+lane], hz = gbase[448+lane], hn = gbase[512+lane];
        float rr = fast_sigmoid(xr + hr + cr);
        float zz = fast_sigmoid(xz + hz + cz);
        float nn = fast_tanh(xn + bin + rr * (hn + bhn));
        hreg = fmaf(zz, hreg - nn, nn);
        float v = hreg * wfc;
        #pragma unroll
        for (int s = 32; s > 0; s >>= 1) v += __shfl_xor(v, s, 64);
        if (lane == 0) outp[b0g + (wave - 4)] = v + b_fc[0];
    }
}

#define PASS(sink) (const float*)d_in[0], \
    (const float*)d_in[1], (const float*)d_in[2], (const float*)d_in[3], \
    (const float*)d_in[4], (const float*)d_in[5], (const float*)d_in[6], \
    (const float*)d_in[7], (const float*)d_in[8], (const float*)d_in[9], \
    (const float*)d_in[10], (sink)

extern "C" void kernel_launch(void* const* d_in, const int* in_sizes, int n_in,
                              void* d_out, int out_size, void* d_ws, size_t ws_size,
                              hipStream_t stream) {
    (void)in_sizes; (void)n_in; (void)out_size;
    float* sink = (ws_size >= 4 * 2048 * sizeof(float)) ? (float*)d_ws : nullptr;
    gru_abl<0><<<256, 512, 0, stream>>>(PASS(sink ? sink + 0    : nullptr));
    gru_abl<1><<<256, 512, 0, stream>>>(PASS(sink ? sink + 2048 : nullptr));
    gru_abl<2><<<256, 512, 0, stream>>>(PASS(sink ? sink + 4096 : nullptr));
    gru_abl<4><<<256, 512, 0, stream>>>(PASS(sink ? sink + 6144 : nullptr));
    gru_v5    <<<512, 512, 0, stream>>>(PASS((float*)d_out));
}

// Round 8
// 1776.216 us; speedup vs baseline: 2.1247x; 2.1247x over previous
//
#include <hip/hip_runtime.h>

#define H    64
#define TT   1024
#define NW   512    // 8 waves
#define NWG  256
#define HRUS 144    // h row stride in ushorts (288 B; 72 dwords == 8 mod 32 banks)

typedef float  f32x4  __attribute__((ext_vector_type(4)));
typedef __bf16 bf16x8 __attribute__((ext_vector_type(8)));

__device__ __forceinline__ unsigned short bf16_rne(float f) {
    unsigned u = __float_as_uint(f);
    u += 0x7FFFu + ((u >> 16) & 1u);
    return (unsigned short)(u >> 16);
}
__device__ __forceinline__ float fast_sigmoid(float x) {
    return __builtin_amdgcn_rcpf(1.0f + __expf(-x));
}
__device__ __forceinline__ float fast_tanh(float x) {
    float xx = fminf(fmaxf(x, -15.0f), 15.0f);
    float e  = __expf(2.0f * xx);
    return (e - 1.0f) * __builtin_amdgcn_rcpf(e + 1.0f);
}

// Fused owner-computes structure (NO gate LDS buffer, ONE barrier/step):
//   Waves 0-3 (grp A): layer-0 j-block w = {Whh0 r,z,n tiles}; lane (q,r) gets
//     D[k] = gh0 gate-col j=16w+4q+k, batch r&7 -> gate entirely in registers ->
//     h0 written to hB (rows 0-7, bf16 hi|lo).
//   Waves 4-7 (grp B): layer-1 j-block = 6 tiles {Wih1 r,z,n ; Whh1 r,z,n};
//     gx uses h0-frag (rows b), gh uses h1-frag (rows 8+b, second read) -> gate
//     in registers -> h1 to rows 8-15.
//   hB double-buffered: iter t reads hB[t&1] (h0(t-1), h1(t-2)), writes hB[(t+1)&1].
//   Skew: A active t<TT (makes h0(t)), B active t>=1 (makes h1(t-1)); loop to t=TT.
// Split-bf16 (unchanged numerics): w*h ~= whi*hhi + whi*hlo + wlo*hhi.
__global__ __launch_bounds__(NW, 2) void gru_fuse6(
    const float* __restrict__ x,
    const float* __restrict__ w_ih0, const float* __restrict__ w_hh0,
    const float* __restrict__ b_ih0, const float* __restrict__ b_hh0,
    const float* __restrict__ w_ih1, const float* __restrict__ w_hh1,
    const float* __restrict__ b_ih1, const float* __restrict__ b_hh1,
    const float* __restrict__ w_fc,  const float* __restrict__ b_fc,
    float* __restrict__ out)
{
    __shared__ __align__(16) float          xs[8 * TT];          // 32 KB
    __shared__ __align__(16) unsigned short hB[2][16 * HRUS];    // 9 KB

    const int tid  = threadIdx.x;
    const int wave = tid >> 6;
    const int lane = tid & 63;
    const int r    = lane & 15;
    const int q    = lane >> 4;
    const int b    = r & 7;
    const int b0g  = blockIdx.x * 8;
    const bool grpB = (wave >= 4);
    const int  w4   = wave & 3;
    const int  jb   = 16 * w4 + 4 * q;      // gate cols jb..jb+3 for this lane

    {   // zero both h buffers
        unsigned short* hz = &hB[0][0];
        for (int i = tid; i < 2 * 16 * HRUS; i += NW) hz[i] = 0;
    }
    {   // stage x: wave w copies batch row b0g+w
        const float* xrow = x + (size_t)(b0g + wave) * TT;
        float* xd = xs + wave * TT;
        #pragma unroll
        for (int u = 0; u < 4; ++u) {
            int idx = (u * 64 + lane) * 4;
            *(float4*)(xd + idx) = *(const float4*)(xrow + idx);
        }
    }

    // ---- weight fragments, 6 slots, built unconditionally (uniform -> resident) ----
    // slot i: rows 64*(i%3) + 16*w4 + r of: A: w_hh0 (3-5 duplicate 0-2, unused);
    //                                       B: i<3 w_ih1, i>=3 w_hh1.
    bf16x8 whi[6][2], wlo[6][2];
    #pragma unroll
    for (int i = 0; i < 6; ++i) {
        const float* W = grpB ? ((i < 3) ? w_ih1 : w_hh1) : w_hh0;
        const int row0 = 64 * (i % 3) + 16 * w4;
        #pragma unroll
        for (int c = 0; c < 2; ++c) {
            const float* wp = W + (row0 + r) * H + 32 * c + 8 * q;
            float4 p0 = *(const float4*)wp;
            float4 p1 = *(const float4*)(wp + 4);
            float f[8] = {p0.x,p0.y,p0.z,p0.w,p1.x,p1.y,p1.z,p1.w};
            unsigned short uh[8], ul[8];
            #pragma unroll
            for (int j = 0; j < 8; ++j) {
                unsigned short h16 = bf16_rne(f[j]);
                uh[j] = h16;
                ul[j] = bf16_rne(f[j] - __uint_as_float((unsigned)h16 << 16));
            }
            whi[i][c] = *(const bf16x8*)uh;
            wlo[i][c] = *(const bf16x8*)ul;
        }
    }

    // ---- gate constants for 4 owned hidden units ----
    float gwr[4], gwz[4], gwn[4], gcr[4], gcz[4], gbn[4], ghn[4];
    #pragma unroll
    for (int k = 0; k < 4; ++k) {
        const int j = jb + k;
        if (grpB) {
            gwr[k] = gwz[k] = gwn[k] = 0.0f;
            gcr[k] = b_ih1[j]      + b_hh1[j];
            gcz[k] = b_ih1[64+j]   + b_hh1[64+j];
            gbn[k] = b_ih1[128+j];
            ghn[k] = b_hh1[128+j];
        } else {
            gwr[k] = w_ih0[j]; gwz[k] = w_ih0[64+j]; gwn[k] = w_ih0[128+j];
            gcr[k] = b_ih0[j]      + b_hh0[j];
            gcz[k] = b_ih0[64+j]   + b_hh0[64+j];
            gbn[k] = b_ih0[128+j];
            ghn[k] = b_hh0[128+j];
        }
    }
    const float wfc = w_fc[lane];

    float hst[4] = {0.0f, 0.0f, 0.0f, 0.0f};   // this lane's 4 hidden units
    __syncthreads();

    #pragma unroll 1
    for (int t = 0; t <= TT; ++t) {
        const unsigned short* src = hB[t & 1];
        unsigned short*       dst = hB[(t + 1) & 1];
        const bool act = grpB ? (t >= 1) : (t < TT);
        if (act) {
            // B-frag from h0 rows (replicated across both lane halves)
            const unsigned short* f0 = src + b * HRUS;
            const bf16x8 a_h0 = *(const bf16x8*)(f0 + 8 * q);
            const bf16x8 a_h1 = *(const bf16x8*)(f0 + 32 + 8 * q);
            const bf16x8 a_l0 = *(const bf16x8*)(f0 + 64 + 8 * q);
            const bf16x8 a_l1 = *(const bf16x8*)(f0 + 96 + 8 * q);

            f32x4 d0 = {0,0,0,0}, d1 = {0,0,0,0}, d2 = {0,0,0,0};
            d0 = __builtin_amdgcn_mfma_f32_16x16x32_bf16(whi[0][0], a_h0, d0, 0,0,0);
            d0 = __builtin_amdgcn_mfma_f32_16x16x32_bf16(whi[0][1], a_h1, d0, 0,0,0);
            d0 = __builtin_amdgcn_mfma_f32_16x16x32_bf16(whi[0][0], a_l0, d0, 0,0,0);
            d0 = __builtin_amdgcn_mfma_f32_16x16x32_bf16(whi[0][1], a_l1, d0, 0,0,0);
            d0 = __builtin_amdgcn_mfma_f32_16x16x32_bf16(wlo[0][0], a_h0, d0, 0,0,0);
            d0 = __builtin_amdgcn_mfma_f32_16x16x32_bf16(wlo[0][1], a_h1, d0, 0,0,0);
            d1 = __builtin_amdgcn_mfma_f32_16x16x32_bf16(whi[1][0], a_h0, d1, 0,0,0);
            d1 = __builtin_amdgcn_mfma_f32_16x16x32_bf16(whi[1][1], a_h1, d1, 0,0,0);
            d1 = __builtin_amdgcn_mfma_f32_16x16x32_bf16(whi[1][0], a_l0, d1, 0,0,0);
            d1 = __builtin_amdgcn_mfma_f32_16x16x32_bf16(whi[1][1], a_l1, d1, 0,0,0);
            d1 = __builtin_amdgcn_mfma_f32_16x16x32_bf16(wlo[1][0], a_h0, d1, 0,0,0);
            d1 = __builtin_amdgcn_mfma_f32_16x16x32_bf16(wlo[1][1], a_h1, d1, 0,0,0);
            d2 = __builtin_amdgcn_mfma_f32_16x16x32_bf16(whi[2][0], a_h0, d2, 0,0,0);
            d2 = __builtin_amdgcn_mfma_f32_16x16x32_bf16(whi[2][1], a_h1, d2, 0,0,0);
            d2 = __builtin_amdgcn_mfma_f32_16x16x32_bf16(whi[2][0], a_l0, d2, 0,0,0);
            d2 = __builtin_amdgcn_mfma_f32_16x16x32_bf16(whi[2][1], a_l1, d2, 0,0,0);
            d2 = __builtin_amdgcn_mfma_f32_16x16x32_bf16(wlo[2][0], a_h0, d2, 0,0,0);
            d2 = __builtin_amdgcn_mfma_f32_16x16x32_bf16(wlo[2][1], a_h1, d2, 0,0,0);

            if (grpB) {
                // second B-frag from h1 rows (replicated)
                const unsigned short* f1 = src + (8 + b) * HRUS;
                const bf16x8 c_h0 = *(const bf16x8*)(f1 + 8 * q);
                const bf16x8 c_h1 = *(const bf16x8*)(f1 + 32 + 8 * q);
                const bf16x8 c_l0 = *(const bf16x8*)(f1 + 64 + 8 * q);
                const bf16x8 c_l1 = *(const bf16x8*)(f1 + 96 + 8 * q);
                f32x4 d3 = {0,0,0,0}, d4 = {0,0,0,0}, d5 = {0,0,0,0};
                d3 = __builtin_amdgcn_mfma_f32_16x16x32_bf16(whi[3][0], c_h0, d3, 0,0,0);
                d3 = __builtin_amdgcn_mfma_f32_16x16x32_bf16(whi[3][1], c_h1, d3, 0,0,0);
                d3 = __builtin_amdgcn_mfma_f32_16x16x32_bf16(whi[3][0], c_l0, d3, 0,0,0);
                d3 = __builtin_amdgcn_mfma_f32_16x16x32_bf16(whi[3][1], c_l1, d3, 0,0,0);
                d3 = __builtin_amdgcn_mfma_f32_16x16x32_bf16(wlo[3][0], c_h0, d3, 0,0,0);
                d3 = __builtin_amdgcn_mfma_f32_16x16x32_bf16(wlo[3][1], c_h1, d3, 0,0,0);
                d4 = __builtin_amdgcn_mfma_f32_16x16x32_bf16(whi[4][0], c_h0, d4, 0,0,0);
                d4 = __builtin_amdgcn_mfma_f32_16x16x32_bf16(whi[4][1], c_h1, d4, 0,0,0);
                d4 = __builtin_amdgcn_mfma_f32_16x16x32_bf16(whi[4][0], c_l0, d4, 0,0,0);
                d4 = __builtin_amdgcn_mfma_f32_16x16x32_bf16(whi[4][1], c_l1, d4, 0,0,0);
                d4 = __builtin_amdgcn_mfma_f32_16x16x32_bf16(wlo[4][0], c_h0, d4, 0,0,0);
                d4 = __builtin_amdgcn_mfma_f32_16x16x32_bf16(wlo[4][1], c_h1, d4, 0,0,0);
                d5 = __builtin_amdgcn_mfma_f32_16x16x32_bf16(whi[5][0], c_h0, d5, 0,0,0);
                d5 = __builtin_amdgcn_mfma_f32_16x16x32_bf16(whi[5][1], c_h1, d5, 0,0,0);
                d5 = __builtin_amdgcn_mfma_f32_16x16x32_bf16(whi[5][0], c_l0, d5, 0,0,0);
                d5 = __builtin_amdgcn_mfma_f32_16x16x32_bf16(whi[5][1], c_l1, d5, 0,0,0);
                d5 = __builtin_amdgcn_mfma_f32_16x16x32_bf16(wlo[5][0], c_h0, d5, 0,0,0);
                d5 = __builtin_amdgcn_mfma_f32_16x16x32_bf16(wlo[5][1], c_h1, d5, 0,0,0);
                #pragma unroll
                for (int k = 0; k < 4; ++k) {
                    float rr = fast_sigmoid(d0[k] + d3[k] + gcr[k]);
                    float zz = fast_sigmoid(d1[k] + d4[k] + gcz[k]);
                    float nn = fast_tanh(d2[k] + gbn[k] + rr * (d5[k] + ghn[k]));
                    hst[k] = fmaf(zz, hst[k] - nn, nn);
                }
            } else {
                const float xv = xs[b * TT + t];
                #pragma unroll
                for (int k = 0; k < 4; ++k) {
                    float rr = fast_sigmoid(fmaf(xv, gwr[k], gcr[k]) + d0[k]);
                    float zz = fast_sigmoid(fmaf(xv, gwz[k], gcz[k]) + d1[k]);
                    float nn = fast_tanh(fmaf(xv, gwn[k], gbn[k]) + rr * (d2[k] + ghn[k]));
                    hst[k] = fmaf(zz, hst[k] - nn, nn);
                }
            }
            // pack 4 hi + 4 lo, write one b64 each (lanes r<8; batch b, cols jb..jb+3)
            if (r < 8) {
                ushort4 hv, lv;
                {
                    unsigned short h0_ = bf16_rne(hst[0]);
                    unsigned short h1_ = bf16_rne(hst[1]);
                    unsigned short h2_ = bf16_rne(hst[2]);
                    unsigned short h3_ = bf16_rne(hst[3]);
                    hv.x = h0_; hv.y = h1_; hv.z = h2_; hv.w = h3_;
                    lv.x = bf16_rne(hst[0] - __uint_as_float((unsigned)h0_ << 16));
                    lv.y = bf16_rne(hst[1] - __uint_as_float((unsigned)h1_ << 16));
                    lv.z = bf16_rne(hst[2] - __uint_as_float((unsigned)h2_ << 16));
                    lv.w = bf16_rne(hst[3] - __uint_as_float((unsigned)h3_ << 16));
                }
                unsigned short* wdst = dst + ((grpB ? 8 : 0) + b) * HRUS + jb;
                *(ushort4*)(wdst)      = hv;
                *(ushort4*)(wdst + 64) = lv;
            }
        }
        __syncthreads();
    }

    // ---- FC: out[b] = dot(h1(TT-1), w_fc) + b_fc ; h1 final is in hB[1] rows 8-15 ----
    {
        const unsigned short* hrow = hB[(TT + 1) & 1] + (8 + wave) * HRUS;
        float hi = __uint_as_float((unsigned)hrow[lane]      << 16);
        float lo = __uint_as_float((unsigned)hrow[64 + lane] << 16);
        float v = (hi + lo) * wfc;
        #pragma unroll
        for (int s = 32; s > 0; s >>= 1) v += __shfl_xor(v, s, 64);
        if (lane == 0) out[b0g + wave] = v + b_fc[0];
    }
}

extern "C" void kernel_launch(void* const* d_in, const int* in_sizes, int n_in,
                              void* d_out, int out_size, void* d_ws, size_t ws_size,
                              hipStream_t stream) {
    (void)in_sizes; (void)n_in; (void)out_size; (void)d_ws; (void)ws_size;
    gru_fuse6<<<NWG, NW, 0, stream>>>(
        (const float*)d_in[0],
        (const float*)d_in[1], (const float*)d_in[2],
        (const float*)d_in[3], (const float*)d_in[4],
        (const float*)d_in[5], (const float*)d_in[6],
        (const float*)d_in[7], (const float*)d_in[8],
        (const float*)d_in[9], (const float*)d_in[10],
        (float*)d_out);
}

// Round 9
// 1064.416 us; speedup vs baseline: 3.5455x; 1.6687x over previous
//
#include <hip/hip_runtime.h>

#define H    64
#define TT   1024
#define NW   768    // 12 waves: 0-3 = A (layer0), 4-7 = B1 (gx1), 8-11 = B2 (layer1)
#define NWG  256
#define XSTR 1032   // xs row stride (floats); 1032 % 32 == 8 -> batches on distinct banks
#define HRUS 144    // h row stride in ushorts (288 B; 72 dwords == 8 mod 32 banks)

typedef float  f32x4  __attribute__((ext_vector_type(4)));
typedef __bf16 bf16x8 __attribute__((ext_vector_type(8)));

__device__ __forceinline__ unsigned short bf16_rne(float f) {
    unsigned u = __float_as_uint(f);
    u += 0x7FFFu + ((u >> 16) & 1u);
    return (unsigned short)(u >> 16);
}
__device__ __forceinline__ float fast_sigmoid(float x) {
    return __builtin_amdgcn_rcpf(1.0f + __expf(-x));
}
__device__ __forceinline__ float fast_tanh(float x) {
    float xx = fminf(fmaxf(x, -15.0f), 15.0f);
    float e  = __expf(2.0f * xx);
    return (e - 1.0f) * __builtin_amdgcn_rcpf(e + 1.0f);
}

// 3-stage software pipeline, ONE barrier/iter, 3 tiles (=12 frags) per wave:
//   A  (waves 0-3,  j-block w4): d=Whh0·h0(t-1) -> layer0 gate -> h0(t) -> hB dst rows 0-7
//   B1 (waves 4-7,  j-block w4): gx=Wih1·h0(t-1) -> gxb[t&1]   (produces gx1(t-1))
//   B2 (waves 8-11, j-block w4): d=Whh1·h1(t-3), gx1(t-2) from gxb[(t+1)&1] ->
//                                layer1 gate -> h1(t-2) -> hB dst rows 8-15
// D-mapping (R4-verified): lane(q=lane>>4, r=lane&15) holds D[4q+k][col=r], col=batch r&7
// (B-frag rows replicated across lane halves). Owner lane does the gate for
// j = 16*w4 + 4q + k, batch r&7, entirely in registers. Split-bf16 numerics unchanged.
__global__ __launch_bounds__(NW, 2) void gru_pipe7(
    const float* __restrict__ x,
    const float* __restrict__ w_ih0, const float* __restrict__ w_hh0,
    const float* __restrict__ b_ih0, const float* __restrict__ b_hh0,
    const float* __restrict__ w_ih1, const float* __restrict__ w_hh1,
    const float* __restrict__ b_ih1, const float* __restrict__ b_hh1,
    const float* __restrict__ w_fc,  const float* __restrict__ b_fc,
    float* __restrict__ out)
{
    __shared__ __align__(16) float          xs[8 * XSTR];          // 33 KB
    __shared__ __align__(16) unsigned short hB[2][16 * HRUS];      // 9.2 KB
    __shared__ __align__(16) float          gxb[2 * 4 * 3 * 4 * 8 * 4];  // 24 KB

    const int tid  = threadIdx.x;
    const int wave = tid >> 6;
    const int lane = tid & 63;
    const int r    = lane & 15;
    const int q    = lane >> 4;
    const int b    = r & 7;
    const int b0g  = blockIdx.x * 8;
    const int g    = wave >> 2;          // 0=A, 1=B1, 2=B2
    const int w4   = wave & 3;
    const int jb   = 16 * w4 + 4 * q;    // owned gate cols jb..jb+3

    for (int i = tid; i < 2 * 16 * HRUS; i += NW) (&hB[0][0])[i] = 0;
    for (int i = tid; i < 2*4*3*4*8*4;  i += NW) gxb[i] = 0.0f;

    if (wave < 8) {   // stage x: wave w copies batch row b0g+w
        const float* xrow = x + (size_t)(b0g + wave) * TT;
        float* xd = xs + wave * XSTR;
        #pragma unroll
        for (int u = 0; u < 4; ++u) {
            int idx = (u * 64 + lane) * 4;
            *(float4*)(xd + idx) = *(const float4*)(xrow + idx);
        }
    }

    // ---- weight fragments: 3 tiles (r,z,n) per wave ----
    const float* W = (g == 0) ? w_hh0 : (g == 1) ? w_ih1 : w_hh1;
    bf16x8 whi[3][2], wlo[3][2];
    #pragma unroll
    for (int i = 0; i < 3; ++i) {
        const int row0 = 64 * i + 16 * w4;
        #pragma unroll
        for (int c = 0; c < 2; ++c) {
            const float* wp = W + (row0 + r) * H + 32 * c + 8 * q;
            float4 p0 = *(const float4*)wp;
            float4 p1 = *(const float4*)(wp + 4);
            float f[8] = {p0.x,p0.y,p0.z,p0.w,p1.x,p1.y,p1.z,p1.w};
            unsigned short uh[8], ul[8];
            #pragma unroll
            for (int j = 0; j < 8; ++j) {
                unsigned short h16 = bf16_rne(f[j]);
                uh[j] = h16;
                ul[j] = bf16_rne(f[j] - __uint_as_float((unsigned)h16 << 16));
            }
            whi[i][c] = *(const bf16x8*)uh;
            wlo[i][c] = *(const bf16x8*)ul;
        }
    }

    // ---- gate constants for the 4 owned units (A: layer0, B2: layer1) ----
    float gwr[4], gwz[4], gwn[4], gcr[4], gcz[4], gbn[4], ghn[4];
    #pragma unroll
    for (int k = 0; k < 4; ++k) {
        const int j = jb + k;
        if (g == 0) {
            gwr[k] = w_ih0[j]; gwz[k] = w_ih0[64+j]; gwn[k] = w_ih0[128+j];
            gcr[k] = b_ih0[j]      + b_hh0[j];
            gcz[k] = b_ih0[64+j]   + b_hh0[64+j];
            gbn[k] = b_ih0[128+j];
            ghn[k] = b_hh0[128+j];
        } else if (g == 2) {
            gwr[k] = gwz[k] = gwn[k] = 0.0f;
            gcr[k] = b_ih1[j]      + b_hh1[j];
            gcz[k] = b_ih1[64+j]   + b_hh1[64+j];
            gbn[k] = b_ih1[128+j];
            ghn[k] = b_hh1[128+j];
        } else {
            gwr[k] = gwz[k] = gwn[k] = 0.0f;
            gcr[k] = gcz[k] = gbn[k] = ghn[k] = 0.0f;
        }
    }
    const float wfc = w_fc[lane];

    // B-frag source row: A,B1 read h0 (rows b); B2 reads h1 (rows 8+b)
    const int rowbase = ((g == 2) ? (8 + b) : b) * HRUS;
    // gxb lane offsets: (slot, w4, type, q, b) -> dwords
    const int gxlane = ((w4 * 3) * 4 + q) * 8 * 4 + b * 4;   // + slot*1536 + type*128
    float* gxw = gxb + gxlane;                                // B1 write base
    const float* gxr = gxb + gxlane;                          // B2 read base (slot added per-iter)

    float hst[4] = {0.0f, 0.0f, 0.0f, 0.0f};
    __syncthreads();

    #pragma unroll 1
    for (int t = 0; t <= TT + 1; ++t) {
        const unsigned short* src = hB[t & 1];
        unsigned short*       dst = hB[(t + 1) & 1];
        const bool act = (g == 0) ? (t < TT)
                       : (g == 1) ? (t >= 1 && t <= TT)
                                  : (t >= 2);
        if (act) {
            const unsigned short* f0 = src + rowbase;
            const bf16x8 hh0 = *(const bf16x8*)(f0 + 8 * q);
            const bf16x8 hh1 = *(const bf16x8*)(f0 + 32 + 8 * q);
            const bf16x8 hl0 = *(const bf16x8*)(f0 + 64 + 8 * q);
            const bf16x8 hl1 = *(const bf16x8*)(f0 + 96 + 8 * q);

            f32x4 d0 = {0,0,0,0}, d1 = {0,0,0,0}, d2 = {0,0,0,0};
            d0 = __builtin_amdgcn_mfma_f32_16x16x32_bf16(whi[0][0], hh0, d0, 0,0,0);
            d1 = __builtin_amdgcn_mfma_f32_16x16x32_bf16(whi[1][0], hh0, d1, 0,0,0);
            d2 = __builtin_amdgcn_mfma_f32_16x16x32_bf16(whi[2][0], hh0, d2, 0,0,0);
            d0 = __builtin_amdgcn_mfma_f32_16x16x32_bf16(whi[0][1], hh1, d0, 0,0,0);
            d1 = __builtin_amdgcn_mfma_f32_16x16x32_bf16(whi[1][1], hh1, d1, 0,0,0);
            d2 = __builtin_amdgcn_mfma_f32_16x16x32_bf16(whi[2][1], hh1, d2, 0,0,0);
            d0 = __builtin_amdgcn_mfma_f32_16x16x32_bf16(whi[0][0], hl0, d0, 0,0,0);
            d1 = __builtin_amdgcn_mfma_f32_16x16x32_bf16(whi[1][0], hl0, d1, 0,0,0);
            d2 = __builtin_amdgcn_mfma_f32_16x16x32_bf16(whi[2][0], hl0, d2, 0,0,0);
            d0 = __builtin_amdgcn_mfma_f32_16x16x32_bf16(whi[0][1], hl1, d0, 0,0,0);
            d1 = __builtin_amdgcn_mfma_f32_16x16x32_bf16(whi[1][1], hl1, d1, 0,0,0);
            d2 = __builtin_amdgcn_mfma_f32_16x16x32_bf16(whi[2][1], hl1, d2, 0,0,0);
            d0 = __builtin_amdgcn_mfma_f32_16x16x32_bf16(wlo[0][0], hh0, d0, 0,0,0);
            d1 = __builtin_amdgcn_mfma_f32_16x16x32_bf16(wlo[1][0], hh0, d1, 0,0,0);
            d2 = __builtin_amdgcn_mfma_f32_16x16x32_bf16(wlo[2][0], hh0, d2, 0,0,0);
            d0 = __builtin_amdgcn_mfma_f32_16x16x32_bf16(wlo[0][1], hh1, d0, 0,0,0);
            d1 = __builtin_amdgcn_mfma_f32_16x16x32_bf16(wlo[1][1], hh1, d1, 0,0,0);
            d2 = __builtin_amdgcn_mfma_f32_16x16x32_bf16(wlo[2][1], hh1, d2, 0,0,0);

            if (g == 1) {
                if (r < 8) {   // publish gx1(t-1) to slot t&1
                    float* p = gxw + (t & 1) * 1536;
                    *(f32x4*)(p)       = d0;
                    *(f32x4*)(p + 128) = d1;
                    *(f32x4*)(p + 256) = d2;
                }
            } else {
                float er[4], ez[4], en[4];
                if (g == 0) {
                    const float xv = xs[b * XSTR + t];
                    #pragma unroll
                    for (int k = 0; k < 4; ++k) {
                        er[k] = fmaf(xv, gwr[k], gcr[k]);
                        ez[k] = fmaf(xv, gwz[k], gcz[k]);
                        en[k] = fmaf(xv, gwn[k], gbn[k]);
                    }
                } else {       // consume gx1(t-2) from slot (t+1)&1
                    const float* p = gxr + ((t + 1) & 1) * 1536;
                    const f32x4 gx0 = *(const f32x4*)(p);
                    const f32x4 gx1 = *(const f32x4*)(p + 128);
                    const f32x4 gx2 = *(const f32x4*)(p + 256);
                    #pragma unroll
                    for (int k = 0; k < 4; ++k) {
                        er[k] = gx0[k] + gcr[k];
                        ez[k] = gx1[k] + gcz[k];
                        en[k] = gx2[k] + gbn[k];
                    }
                }
                #pragma unroll
                for (int k = 0; k < 4; ++k) {
                    float rr = fast_sigmoid(er[k] + d0[k]);
                    float zz = fast_sigmoid(ez[k] + d1[k]);
                    float nn = fast_tanh(en[k] + rr * (d2[k] + ghn[k]));
                    hst[k] = fmaf(zz, hst[k] - nn, nn);
                }
                if (r < 8) {
                    ushort4 hv, lv;
                    unsigned short h0_ = bf16_rne(hst[0]);
                    unsigned short h1_ = bf16_rne(hst[1]);
                    unsigned short h2_ = bf16_rne(hst[2]);
                    unsigned short h3_ = bf16_rne(hst[3]);
                    hv.x = h0_; hv.y = h1_; hv.z = h2_; hv.w = h3_;
                    lv.x = bf16_rne(hst[0] - __uint_as_float((unsigned)h0_ << 16));
                    lv.y = bf16_rne(hst[1] - __uint_as_float((unsigned)h1_ << 16));
                    lv.z = bf16_rne(hst[2] - __uint_as_float((unsigned)h2_ << 16));
                    lv.w = bf16_rne(hst[3] - __uint_as_float((unsigned)h3_ << 16));
                    unsigned short* wdst = dst + ((g == 2 ? 8 : 0) + b) * HRUS + jb;
                    *(ushort4*)(wdst)      = hv;
                    *(ushort4*)(wdst + 64) = lv;
                }
            }
        }
        __syncthreads();
    }

    // ---- FC: h1(TT-1) sits in hB[(TT+2)&1] == hB[0], rows 8-15 ----
    if (wave < 8) {
        const unsigned short* hrow = hB[0] + (8 + wave) * HRUS;
        float hi = __uint_as_float((unsigned)hrow[lane]      << 16);
        float lo = __uint_as_float((unsigned)hrow[64 + lane] << 16);
        float v = (hi + lo) * wfc;
        #pragma unroll
        for (int s = 32; s > 0; s >>= 1) v += __shfl_xor(v, s, 64);
        if (lane == 0) out[b0g + wave] = v + b_fc[0];
    }
}

extern "C" void kernel_launch(void* const* d_in, const int* in_sizes, int n_in,
                              void* d_out, int out_size, void* d_ws, size_t ws_size,
                              hipStream_t stream) {
    (void)in_sizes; (void)n_in; (void)out_size; (void)d_ws; (void)ws_size;
    gru_pipe7<<<NWG, NW, 0, stream>>>(
        (const float*)d_in[0],
        (const float*)d_in[1], (const float*)d_in[2],
        (const float*)d_in[3], (const float*)d_in[4],
        (const float*)d_in[5], (const float*)d_in[6],
        (const float*)d_in[7], (const float*)d_in[8],
        (const float*)d_in[9], (const float*)d_in[10],
        (float*)d_out);
}